// Round 17
// baseline (265.160 us; speedup 1.0000x reference)
//
#include <hip/hip_runtime.h>
#include <hip/hip_bf16.h>
#include <math.h>

#define N_NODES 50000
#define N_EDGES 800000
#define F_IN 128
#define NBUCK 391            // ceil(50000/128) buckets of 128 dst nodes
#define EPB 4096             // edges per block in bucket build
#define NBB 196              // ceil(800000/4096)

typedef __attribute__((ext_vector_type(8))) short bf16x8;
typedef __attribute__((ext_vector_type(4))) float f32x4;
typedef __attribute__((ext_vector_type(2))) float f32x2;
typedef unsigned long long ull;

__device__ __forceinline__ float elu_f(float x)   { return x > 0.f ? x : expm1f(x); }
__device__ __forceinline__ float lrelu_f(float x) { return x > 0.f ? x : 0.2f * x; }
__device__ __forceinline__ int   clampN(int v)    { return v < 0 ? 0 : (v >= N_NODES ? N_NODES - 1 : v); }
__device__ __forceinline__ float bits2f(unsigned int u) { union { unsigned int u; float f; } x; x.u = u; return x.f; }
__device__ __forceinline__ float bf2f(unsigned short s) { return bits2f(((unsigned int)s) << 16); }
__device__ __forceinline__ unsigned short f2bfbits(float f) {
    __hip_bfloat16 b = __float2bfloat16(f);
    return __builtin_bit_cast(unsigned short, b);
}
__device__ __forceinline__ unsigned int pack2(float lo, float hi) {
    return ((unsigned int)f2bfbits(hi) << 16) | f2bfbits(lo);
}

// ---------------- merged prep: hist partials (blocks <NBB) + cast + red zero ----------------
#define CAST_X_IDS (N_NODES * 32)
#define CAST_IDS (CAST_X_IDS + 32768 + 8192 + 4096)
#define CASTB ((CAST_IDS + 255) / 256)
__global__ __launch_bounds__(256) void k_prep(const int* __restrict__ dst,
                                              const float* __restrict__ x,
                                              const float* __restrict__ W_rel,
                                              const float* __restrict__ W_root,
                                              const float* __restrict__ W1,
                                              const float* __restrict__ W2,
                                              int* __restrict__ part,
                                              __hip_bfloat16* __restrict__ Abuf,
                                              unsigned int* __restrict__ x8,
                                              __hip_bfloat16* __restrict__ Wc,
                                              __hip_bfloat16* __restrict__ W1b,
                                              __hip_bfloat16* __restrict__ W2b,
                                              float* __restrict__ red) {
    __shared__ int hist[NBUCK];
    int tid = threadIdx.x;
    if (blockIdx.x < NBB) {
        for (int j = tid; j < NBUCK; j += 256) hist[j] = 0;
        __syncthreads();
        int base = blockIdx.x * EPB;
        #pragma unroll
        for (int t = 0; t < EPB / 256; ++t) {
            int e = base + t * 256 + tid;
            if (e < N_EDGES) atomicAdd(&hist[clampN(dst[e]) >> 7], 1);
        }
        __syncthreads();
        for (int j = tid; j < NBUCK; j += 256)
            part[(size_t)blockIdx.x * NBUCK + j] = hist[j];
    } else {
        if (blockIdx.x == NBB) red[tid] = 0.f;
        int id = (blockIdx.x - NBB) * 256 + tid;
        if (id < CAST_X_IDS) {
            int i = id >> 5, c4 = (id & 31) * 4;
            float4 v = *(const float4*)&x[(size_t)i * 128 + c4];
            ull p = (ull)f2bfbits(v.x) | ((ull)f2bfbits(v.y) << 16)
                  | ((ull)f2bfbits(v.z) << 32) | ((ull)f2bfbits(v.w) << 48);
            *(ull*)&Abuf[(size_t)i * 256 + 128 + c4] = p;
            int t = __builtin_amdgcn_cvt_pk_fp8_f32(v.x, v.y, 0, false);
            t = __builtin_amdgcn_cvt_pk_fp8_f32(v.z, v.w, t, true);
            x8[(size_t)i * 32 + (id & 31)] = (unsigned int)t;
        } else if (id < CAST_IDS) {
            int j = id - CAST_X_IDS;
            if (j < 32768) {
                int cc = j >> 8, k = j & 255;
                float v = (k < 128) ? W_rel[cc * 128 + k] : W_root[cc * 128 + (k - 128)];
                Wc[j] = __float2bfloat16(v);
            } else if (j < 32768 + 8192) {
                W1b[j - 32768] = __float2bfloat16(W1[j - 32768]);
            } else {
                W2b[j - 32768 - 8192] = __float2bfloat16(W2[j - 32768 - 8192]);
            }
        }
    }
}

// ---------------- bucket scan: reduce partials + exclusive scan ----------------
__global__ __launch_bounds__(512) void k_bscan(const int* __restrict__ part,
                                               int* __restrict__ boff,
                                               int* __restrict__ bcur) {
    __shared__ int wsum[8];
    __shared__ int wbase[8];
    int tid = threadIdx.x;
    int lane = tid & 63, wid = tid >> 6;
    int v = 0;
    if (tid < NBUCK) {
        for (int b = 0; b < NBB; ++b) v += part[(size_t)b * NBUCK + tid];
    }
    int x = v;
    #pragma unroll
    for (int d = 1; d < 64; d <<= 1) {
        int t = __shfl_up(x, d, 64);
        if (lane >= d) x += t;
    }
    if (lane == 63) wsum[wid] = x;
    __syncthreads();
    if (tid == 0) {
        int b = 0;
        #pragma unroll
        for (int w = 0; w < 8; ++w) { wbase[w] = b; b += wsum[w]; }
    }
    __syncthreads();
    if (tid < NBUCK) {
        int e = wbase[wid] + x - v;
        boff[tid] = e;
        bcur[tid] = e;
    }
    if (tid == 0) boff[NBUCK] = N_EDGES;
}

// scatter packed (src<<7)|(dst&127) into bucket-grouped ebuf
__global__ __launch_bounds__(256) void k_bscatter(const int* __restrict__ src,
                                                  const int* __restrict__ dst,
                                                  int* __restrict__ bcur,
                                                  unsigned int* __restrict__ ebuf) {
    __shared__ int hist[NBUCK];
    __shared__ int hbase[NBUCK];
    int tid = threadIdx.x;
    for (int j = tid; j < NBUCK; j += 256) hist[j] = 0;
    __syncthreads();
    int base = blockIdx.x * EPB;
    unsigned int myP[EPB / 256]; int myB[EPB / 256], myR[EPB / 256];
    #pragma unroll
    for (int t = 0; t < EPB / 256; ++t) {
        int e = base + t * 256 + tid;
        if (e < N_EDGES) {
            int d = clampN(dst[e]);
            int s = clampN(src[e]);
            myP[t] = ((unsigned int)s << 7) | (unsigned int)(d & 127);
            myB[t] = d >> 7;
            myR[t] = atomicAdd(&hist[d >> 7], 1);
        } else myB[t] = -1;
    }
    __syncthreads();
    for (int j = tid; j < NBUCK; j += 256)
        if (hist[j]) hbase[j] = atomicAdd(&bcur[j], hist[j]);
    __syncthreads();
    #pragma unroll
    for (int t = 0; t < EPB / 256; ++t) {
        if (myB[t] >= 0) ebuf[hbase[myB[t]] + myR[t]] = myP[t];
    }
}

__global__ __launch_bounds__(256) void k_bfinal(const unsigned int* __restrict__ ebuf,
                                                const int* __restrict__ boff,
                                                int* __restrict__ offsets,
                                                int* __restrict__ csr) {
    __shared__ int cnt[128];
    __shared__ int cur[128];
    __shared__ int ws[4];
    int b = blockIdx.x;
    int tid = threadIdx.x;
    int node0 = b << 7;
    int k0 = boff[b], k1 = boff[b + 1];
    if (tid < 128) cnt[tid] = 0;
    __syncthreads();
    for (int k = k0 + tid; k < k1; k += 256)
        atomicAdd(&cnt[ebuf[k] & 127u], 1);
    __syncthreads();
    int lane = tid & 63;
    int v = (tid < 128) ? cnt[tid] : 0;
    int x = v;
    #pragma unroll
    for (int d = 1; d < 64; d <<= 1) {
        int t = __shfl_up(x, d, 64);
        if (lane >= d) x += t;
    }
    if (lane == 63) ws[tid >> 6] = x;
    __syncthreads();
    if (tid < 128) {
        int add = (tid >> 6) ? ws[0] : 0;
        int excl = k0 + add + x - v;
        cur[tid] = excl;
        int node = node0 + tid;
        if (node < N_NODES) offsets[node] = excl;
    }
    if (b == NBUCK - 1 && tid == 0) offsets[N_NODES] = N_EDGES;
    __syncthreads();
    for (int k = k0 + tid; k < k1; k += 256) {
        unsigned int e = ebuf[k];
        int r = atomicAdd(&cur[e & 127u], 1);
        csr[r] = (int)(e >> 7);
    }
}

// ---------------- GraphConv gather: fp8 x rows, 2 nodes/wave, predicated unroll 8 ----------------
__global__ __launch_bounds__(256) void k_gather(const unsigned int* __restrict__ x8,
                                                const int* __restrict__ offsets,
                                                const int* __restrict__ csr,
                                                ull* __restrict__ outNbr) {
    int i = blockIdx.x * 8 + (threadIdx.x >> 5);
    int l = threadIdx.x & 31;          // fp8 u32 word: channels 4l..4l+3
    int k0 = offsets[i], k1 = offsets[i + 1];
    float a0 = 0.f, a1 = 0.f, a2 = 0.f, a3 = 0.f;
    for (int kb = k0; kb < k1; kb += 8) {
        int s[8]; int vm[8];
        #pragma unroll
        for (int j = 0; j < 8; ++j) {
            int kk = kb + j;
            vm[j] = kk < k1;
            s[j] = csr[vm[j] ? kk : k1 - 1];
        }
        unsigned int u[8];
        #pragma unroll
        for (int j = 0; j < 8; ++j) u[j] = x8[(size_t)s[j] * 32 + l];
        #pragma unroll
        for (int j = 0; j < 8; ++j) {
            if (vm[j]) {
                f32x2 lo = __builtin_amdgcn_cvt_pk_f32_fp8(u[j], false);
                f32x2 hi = __builtin_amdgcn_cvt_pk_f32_fp8(u[j], true);
                a0 += lo.x; a1 += lo.y; a2 += hi.x; a3 += hi.y;
            }
        }
    }
    outNbr[(size_t)i * 64 + l] = (ull)pack2(a0, a1) | ((ull)pack2(a2, a3) << 32);
}

// ---------------- MFMA GEMM with LDS staging + optional fused alpha/fp8 epilogue ----------------
// EPI: 0 = plain bf16 output (ELU/BIAS apply); 1 = GAT1 alpha (8 heads) + fp8 z; 2 = GAT2 alpha (1 head) + fp8 z.
template<int K, int N, bool ELU, bool BIAS, int EPI>
__global__ __launch_bounds__(256) void k_gemm(const __hip_bfloat16* __restrict__ A,
                                              const __hip_bfloat16* __restrict__ W,
                                              const float* __restrict__ bias,
                                              __hip_bfloat16* __restrict__ Out,
                                              const float* __restrict__ a_src,
                                              const float* __restrict__ a_dst,
                                              float* __restrict__ as_o,
                                              float* __restrict__ ad_o,
                                              unsigned int* __restrict__ z8) {
    constexpr int NT = N / 16;
    __shared__ __align__(16) short smem[64 * 40 + N * 40];
    short (*sA)[40] = (short(*)[40])smem;
    short (*sW)[40] = (short(*)[40])(smem + 64 * 40);
    int tid = threadIdx.x;
    int lane = tid & 63, wave = tid >> 6;
    int quad = lane >> 4, l16 = lane & 15;
    int node0 = blockIdx.x * 64;
    int srow = tid >> 2, schk = (tid & 3) * 8;
    int ga = node0 + srow; if (ga >= N_NODES) ga = N_NODES - 1;
    const short* Ap = (const short*)A + (size_t)ga * K + schk;
    const short* Wp = (const short*)W;
    f32x4 acc[NT];
    #pragma unroll
    for (int t = 0; t < NT; ++t) acc[t] = (f32x4){0.f, 0.f, 0.f, 0.f};
    for (int k0 = 0; k0 < K; k0 += 32) {
        *(bf16x8*)&sA[srow][schk] = *(const bf16x8*)(Ap + k0);
        #pragma unroll
        for (int it = 0; it < N / 64; ++it) {
            int wrow = srow + it * 64;
            *(bf16x8*)&sW[wrow][schk] = *(const bf16x8*)(Wp + (size_t)wrow * K + k0 + schk);
        }
        __syncthreads();
        bf16x8 a = *(const bf16x8*)&sA[wave * 16 + l16][quad * 8];
        #pragma unroll
        for (int nt = 0; nt < NT; ++nt) {
            bf16x8 b = *(const bf16x8*)&sW[nt * 16 + l16][quad * 8];
            acc[nt] = __builtin_amdgcn_mfma_f32_16x16x32_bf16(a, b, acc[nt], 0, 0, 0);
        }
        __syncthreads();
    }
    if (EPI == 0) {
        int mbase = node0 + wave * 16 + quad * 4;
        #pragma unroll
        for (int nt = 0; nt < NT; ++nt) {
            int col = nt * 16 + l16;
            float bv = BIAS ? bias[col] : 0.f;
            #pragma unroll
            for (int r = 0; r < 4; ++r) {
                int m = mbase + r;
                if (m < N_NODES) {
                    float v = acc[nt][r] + bv;
                    if (ELU) v = elu_f(v);
                    Out[(size_t)m * N + col] = __float2bfloat16(v);
                }
            }
        }
    } else {
        // stage z tile to LDS (bf16, pitch 72 shorts = 16B-aligned rows), N == 64
        short* sZ = smem;
        #pragma unroll
        for (int nt = 0; nt < NT; ++nt) {
            int col = nt * 16 + l16;
            #pragma unroll
            for (int r = 0; r < 4; ++r) {
                int row = wave * 16 + quad * 4 + r;
                sZ[row * 72 + col] = (short)f2bfbits(acc[nt][r]);
            }
        }
        __syncthreads();
        int row = tid >> 2, chunk = tid & 3;       // 16 cols per thread
        int gi = node0 + row;
        float v[16];
        bf16x8 c0 = *(const bf16x8*)&sZ[row * 72 + chunk * 16];
        bf16x8 c1 = *(const bf16x8*)&sZ[row * 72 + chunk * 16 + 8];
        #pragma unroll
        for (int j = 0; j < 8; ++j) {
            v[j]     = bf2f((unsigned short)c0[j]);
            v[8 + j] = bf2f((unsigned short)c1[j]);
        }
        if (EPI == 1) {
            float ps0 = 0.f, pd0 = 0.f, ps1 = 0.f, pd1 = 0.f;
            #pragma unroll
            for (int j = 0; j < 8; ++j) {
                ps0 += v[j] * a_src[chunk * 16 + j];
                pd0 += v[j] * a_dst[chunk * 16 + j];
                ps1 += v[8 + j] * a_src[chunk * 16 + 8 + j];
                pd1 += v[8 + j] * a_dst[chunk * 16 + 8 + j];
            }
            if (gi < N_NODES) {
                as_o[(size_t)gi * 8 + 2 * chunk]     = ps0;
                as_o[(size_t)gi * 8 + 2 * chunk + 1] = ps1;
                ad_o[(size_t)gi * 8 + 2 * chunk]     = pd0;
                ad_o[(size_t)gi * 8 + 2 * chunk + 1] = pd1;
            }
        } else {
            float ps = 0.f, pd = 0.f;
            #pragma unroll
            for (int j = 0; j < 16; ++j) {
                ps += v[j] * a_src[chunk * 16 + j];
                pd += v[j] * a_dst[chunk * 16 + j];
            }
            ps += __shfl_xor(ps, 1, 64); ps += __shfl_xor(ps, 2, 64);
            pd += __shfl_xor(pd, 1, 64); pd += __shfl_xor(pd, 2, 64);
            if ((tid & 3) == 0 && gi < N_NODES) { as_o[gi] = ps; ad_o[gi] = pd; }
        }
        if (gi < N_NODES) {
            #pragma unroll
            for (int wi = 0; wi < 4; ++wi) {
                int t = __builtin_amdgcn_cvt_pk_fp8_f32(v[4 * wi], v[4 * wi + 1], 0, false);
                t = __builtin_amdgcn_cvt_pk_fp8_f32(v[4 * wi + 2], v[4 * wi + 3], t, true);
                z8[(size_t)gi * 16 + chunk * 4 + wi] = (unsigned int)t;
            }
        }
    }
}

// ---------------- GAT1 attention: fp8 z, 32 lanes/node (2 groups x 16), 8-edge batches/group ----------------
__global__ __launch_bounds__(256) void k_gat1attn(const unsigned int* __restrict__ z8,
                                                  const float* __restrict__ as1,
                                                  const float* __restrict__ ad1,
                                                  const float* __restrict__ b1,
                                                  const int* __restrict__ offsets,
                                                  const int* __restrict__ csr,
                                                  ull* __restrict__ h2u) {
    int i = blockIdx.x * 8 + (threadIdx.x >> 5);
    int w = threadIdx.x & 31;
    int g = w >> 4;                // group 0/1
    int l = w & 15;                // channels 4l..4l+3 ; head hd = l>>1
    int hd = l >> 1;
    int wh = l & 7, slot = l >> 3; // weight phase: 2 slots x 8 heads within group
    int k0 = offsets[i], k1 = offsets[i + 1];
    float ad_h = ad1[(size_t)i * 8 + hd];
    float adw  = ad1[(size_t)i * 8 + wh];
    float e_self = __expf(lrelu_f(as1[(size_t)i * 8 + hd] + ad_h));
    unsigned int uz = z8[(size_t)i * 16 + l];
    f32x2 zlo = __builtin_amdgcn_cvt_pk_f32_fp8(uz, false);
    f32x2 zhi = __builtin_amdgcn_cvt_pk_f32_fp8(uz, true);
    float acc0, acc1, acc2, acc3;
    if (g == 0) {
        acc0 = e_self * zlo.x; acc1 = e_self * zlo.y;
        acc2 = e_self * zhi.x; acc3 = e_self * zhi.y;
    } else { acc0 = acc1 = acc2 = acc3 = 0.f; }
    float denp = 0.f;
    for (int kb = k0 + 8 * g; kb < k1; kb += 16) {
        int sr[4]; float er[4];
        #pragma unroll
        for (int m = 0; m < 4; ++m) {
            int kk = kb + 2 * m + slot;
            bool v = kk < k1;
            int s = csr[v ? kk : k1 - 1];
            sr[m] = s;
            er[m] = v ? __expf(lrelu_f(as1[(size_t)s * 8 + wh] + adw)) : 0.f;
            denp += er[m];
        }
        int sj[8]; float ej[8]; unsigned int u[8];
        #pragma unroll
        for (int m = 0; m < 4; ++m) {
            #pragma unroll
            for (int sb = 0; sb < 2; ++sb) {
                sj[2 * m + sb] = __shfl(sr[m], sb * 8 + hd, 16);
                ej[2 * m + sb] = __shfl(er[m], sb * 8 + hd, 16);
            }
        }
        #pragma unroll
        for (int j = 0; j < 8; ++j) u[j] = z8[(size_t)sj[j] * 16 + l];
        #pragma unroll
        for (int j = 0; j < 8; ++j) {
            f32x2 alo = __builtin_amdgcn_cvt_pk_f32_fp8(u[j], false);
            f32x2 ahi = __builtin_amdgcn_cvt_pk_f32_fp8(u[j], true);
            acc0 += ej[j] * alo.x; acc1 += ej[j] * alo.y;
            acc2 += ej[j] * ahi.x; acc3 += ej[j] * ahi.y;
        }
    }
    // merge the two groups (lane bit 4), then slots (bit 3)
    acc0 += __shfl_xor(acc0, 16, 64);
    acc1 += __shfl_xor(acc1, 16, 64);
    acc2 += __shfl_xor(acc2, 16, 64);
    acc3 += __shfl_xor(acc3, 16, 64);
    denp += __shfl_xor(denp, 16, 64);
    denp += __shfl_xor(denp, 8, 16);
    float den = __shfl(denp, hd, 16) + e_self;
    float inv = 1.f / den;
    if (g == 0) {
        float r0 = elu_f(acc0 * inv + b1[4 * l + 0]);
        float r1 = elu_f(acc1 * inv + b1[4 * l + 1]);
        float r2 = elu_f(acc2 * inv + b1[4 * l + 2]);
        float r3 = elu_f(acc3 * inv + b1[4 * l + 3]);
        h2u[(size_t)i * 16 + l] = (ull)pack2(r0, r1) | ((ull)pack2(r2, r3) << 32);
    }
}

// ---------------- GAT2 attention: fp8 z, 32 lanes/node (2 groups x 16), fused dot ----------------
__global__ __launch_bounds__(256) void k_gat2attn(const unsigned int* __restrict__ z8,
                                                  const float* __restrict__ as2,
                                                  const float* __restrict__ ad2,
                                                  const float* __restrict__ b2,
                                                  const int* __restrict__ offsets,
                                                  const int* __restrict__ csr,
                                                  const float* __restrict__ Wr,
                                                  float* __restrict__ red) {
    int i = blockIdx.x * 8 + (threadIdx.x >> 5);
    int w = threadIdx.x & 31;
    int g = w >> 4;
    int l = w & 15;
    int k0 = offsets[i], k1 = offsets[i + 1];
    float ad = ad2[i];
    float e_self = __expf(lrelu_f(as2[i] + ad));
    unsigned int uz = z8[(size_t)i * 16 + l];
    f32x2 zlo = __builtin_amdgcn_cvt_pk_f32_fp8(uz, false);
    f32x2 zhi = __builtin_amdgcn_cvt_pk_f32_fp8(uz, true);
    float acc0, acc1, acc2, acc3;
    if (g == 0) {
        acc0 = e_self * zlo.x; acc1 = e_self * zlo.y;
        acc2 = e_self * zhi.x; acc3 = e_self * zhi.y;
    } else { acc0 = acc1 = acc2 = acc3 = 0.f; }
    float denp = (g == 0 && l == 0) ? e_self : 0.f;
    for (int kb = k0 + 16 * g; kb < k1; kb += 32) {
        int kk = kb + l;
        bool v = kk < k1;
        int s = csr[v ? kk : k1 - 1];
        float e = v ? __expf(lrelu_f(as2[s] + ad)) : 0.f;
        denp += e;
        int nv = k1 - kb; if (nv > 16) nv = 16;
        for (int j0 = 0; j0 < nv; j0 += 8) {
            int sj[8]; float ej[8]; unsigned int u[8];
            #pragma unroll
            for (int j = 0; j < 8; ++j) {
                int idx = (j0 + j) & 15;
                sj[j] = __shfl(s, idx, 16);
                ej[j] = __shfl(e, idx, 16);
            }
            #pragma unroll
            for (int j = 0; j < 8; ++j) u[j] = z8[(size_t)sj[j] * 16 + l];
            #pragma unroll
            for (int j = 0; j < 8; ++j) {
                f32x2 alo = __builtin_amdgcn_cvt_pk_f32_fp8(u[j], false);
                f32x2 ahi = __builtin_amdgcn_cvt_pk_f32_fp8(u[j], true);
                acc0 += ej[j] * alo.x; acc1 += ej[j] * alo.y;
                acc2 += ej[j] * ahi.x; acc3 += ej[j] * ahi.y;
            }
        }
    }
    acc0 += __shfl_xor(acc0, 16, 64);
    acc1 += __shfl_xor(acc1, 16, 64);
    acc2 += __shfl_xor(acc2, 16, 64);
    acc3 += __shfl_xor(acc3, 16, 64);
    denp += __shfl_xor(denp, 16, 64);
    #pragma unroll
    for (int d = 8; d >= 1; d >>= 1) denp += __shfl_xor(denp, d, 16);
    float inv = 1.f / denp;
    float c = (acc0 * inv + b2[4 * l + 0]) * Wr[4 * l + 0]
            + (acc1 * inv + b2[4 * l + 1]) * Wr[4 * l + 1]
            + (acc2 * inv + b2[4 * l + 2]) * Wr[4 * l + 2]
            + (acc3 * inv + b2[4 * l + 3]) * Wr[4 * l + 3];
    #pragma unroll
    for (int d = 8; d >= 1; d >>= 1) c += __shfl_xor(c, d, 16);
    if (w == 0) atomicAdd(&red[blockIdx.x & 255], c);
}

// ---------------- finalize ----------------
__global__ void k_finalize(const float* __restrict__ red, const float* __restrict__ br,
                           float* __restrict__ out) {
    int t = threadIdx.x;    // 64 threads
    float s = red[t] + red[t + 64] + red[t + 128] + red[t + 192];
    #pragma unroll
    for (int d = 32; d >= 1; d >>= 1) s += __shfl_xor(s, d, 64);
    if (t == 0) out[0] = s * (1.0f / N_NODES) + br[0];
}

extern "C" void kernel_launch(void* const* d_in, const int* in_sizes, int n_in,
                              void* d_out, int out_size, void* d_ws, size_t ws_size,
                              hipStream_t stream) {
    const float* x      = (const float*)d_in[0];
    const int*   edges  = (const int*)d_in[1];
    const float* W_rel  = (const float*)d_in[2];
    const float* b_rel  = (const float*)d_in[3];
    const float* W_root = (const float*)d_in[4];
    const float* W1     = (const float*)d_in[5];
    const float* a1s    = (const float*)d_in[6];
    const float* a1d    = (const float*)d_in[7];
    const float* b1     = (const float*)d_in[8];
    const float* W2     = (const float*)d_in[9];
    const float* a2s    = (const float*)d_in[10];
    const float* a2d    = (const float*)d_in[11];
    const float* b2     = (const float*)d_in[12];
    const float* Wr     = (const float*)d_in[13];
    const float* br     = (const float*)d_in[14];
    float* out = (float*)d_out;

    const int* src = edges;
    const int* dst = edges + N_EDGES;

    char* ws = (char*)d_ws;
    size_t p = 0;
    auto alloc = [&](size_t bytes) -> void* {
        void* r = ws + p;
        p = (p + bytes + 255) & ~(size_t)255;
        return r;
    };
    int*   part    = (int*)alloc((size_t)NBB * NBUCK * 4);          // hist partials
    int*   boff    = (int*)alloc((size_t)(NBUCK + 1) * 4);
    int*   bcur    = (int*)alloc((size_t)NBUCK * 4);
    unsigned int* ebuf = (unsigned int*)alloc((size_t)N_EDGES * 4); // packed (src<<7)|dstlocal
    int*   offsets = (int*)alloc((size_t)(N_NODES + 1) * 4);
    int*   csr     = (int*)alloc((size_t)N_EDGES * 4);
    __hip_bfloat16* Abuf = (__hip_bfloat16*)alloc((size_t)N_NODES * 256 * 2);  // [nbr | x]
    unsigned int* x8 = (unsigned int*)alloc((size_t)N_NODES * 32 * 4);         // fp8 x
    __hip_bfloat16* Wc   = (__hip_bfloat16*)alloc((size_t)128 * 256 * 2);
    __hip_bfloat16* W1b  = (__hip_bfloat16*)alloc((size_t)64 * 128 * 2);
    __hip_bfloat16* W2b  = (__hip_bfloat16*)alloc((size_t)64 * 64 * 2);
    __hip_bfloat16* h    = (__hip_bfloat16*)alloc((size_t)N_NODES * 128 * 2);
    float* as1 = (float*)alloc((size_t)N_NODES * 8 * 4);
    float* ad1 = (float*)alloc((size_t)N_NODES * 8 * 4);
    __hip_bfloat16* h2b  = (__hip_bfloat16*)alloc((size_t)N_NODES * 64 * 2);
    float* as2 = (float*)alloc((size_t)N_NODES * 4);
    float* ad2 = (float*)alloc((size_t)N_NODES * 4);
    unsigned int* z1e8 = (unsigned int*)alloc((size_t)N_NODES * 16 * 4);  // fp8 z1
    unsigned int* z2e8 = (unsigned int*)alloc((size_t)N_NODES * 16 * 4);  // fp8 z2
    float* red = (float*)alloc(256 * 4);

    const int MB  = (N_NODES + 63) / 64;    // 782
    const int NB8 = N_NODES / 8;            // 6250

    k_prep    <<<NBB + CASTB, 256, 0, stream>>>(dst, x, W_rel, W_root, W1, W2,
                                                part, Abuf, x8, Wc, W1b, W2b, red);
    k_bscan   <<<1, 512, 0, stream>>>(part, boff, bcur);
    k_bscatter<<<NBB, 256, 0, stream>>>(src, dst, bcur, ebuf);
    k_bfinal  <<<NBUCK, 256, 0, stream>>>(ebuf, boff, offsets, csr);
    k_gather  <<<NB8, 256, 0, stream>>>(x8, offsets, csr, (ull*)Abuf);
    k_gemm<256, 128, true,  true,  0><<<MB, 256, 0, stream>>>(Abuf, Wc, b_rel, h,
                                                              nullptr, nullptr, nullptr, nullptr, nullptr);
    k_gemm<128, 64,  false, false, 1><<<MB, 256, 0, stream>>>(h, W1b, nullptr, nullptr,
                                                              a1s, a1d, as1, ad1, z1e8);
    k_gat1attn<<<NB8, 256, 0, stream>>>(z1e8, as1, ad1, b1, offsets, csr, (ull*)h2b);
    k_gemm<64, 64, false, false, 2><<<MB, 256, 0, stream>>>(h2b, W2b, nullptr, nullptr,
                                                            a2s, a2d, as2, ad2, z2e8);
    k_gat2attn<<<NB8, 256, 0, stream>>>(z2e8, as2, ad2, b2, offsets, csr, Wr, red);
    k_finalize<<<1, 64, 0, stream>>>(red, br, out);
}

// Round 18
// 240.917 us; speedup vs baseline: 1.1006x; 1.1006x over previous
//
#include <hip/hip_runtime.h>
#include <hip/hip_bf16.h>
#include <math.h>

#define N_NODES 50000
#define N_EDGES 800000
#define F_IN 128
#define NBUCK 391            // ceil(50000/128) buckets of 128 dst nodes
#define EPB 4096             // edges per block in bucket build
#define NBB 196              // ceil(800000/4096)

typedef __attribute__((ext_vector_type(8))) short bf16x8;
typedef __attribute__((ext_vector_type(4))) float f32x4;
typedef __attribute__((ext_vector_type(2))) float f32x2;
typedef unsigned long long ull;

__device__ __forceinline__ float elu_f(float x)   { return x > 0.f ? x : expm1f(x); }
__device__ __forceinline__ float lrelu_f(float x) { return x > 0.f ? x : 0.2f * x; }
__device__ __forceinline__ int   clampN(int v)    { return v < 0 ? 0 : (v >= N_NODES ? N_NODES - 1 : v); }
__device__ __forceinline__ float bits2f(unsigned int u) { union { unsigned int u; float f; } x; x.u = u; return x.f; }
__device__ __forceinline__ float bf2f(unsigned short s) { return bits2f(((unsigned int)s) << 16); }
__device__ __forceinline__ unsigned short f2bfbits(float f) {
    __hip_bfloat16 b = __float2bfloat16(f);
    return __builtin_bit_cast(unsigned short, b);
}
__device__ __forceinline__ unsigned int pack2(float lo, float hi) {
    return ((unsigned int)f2bfbits(hi) << 16) | f2bfbits(lo);
}

// ---------------- merged prep: hist partials (blocks <NBB) + cast + red zero ----------------
#define CAST_X_IDS (N_NODES * 32)
#define CAST_IDS (CAST_X_IDS + 32768 + 8192 + 4096)
#define CASTB ((CAST_IDS + 255) / 256)
__global__ __launch_bounds__(256) void k_prep(const int* __restrict__ dst,
                                              const float* __restrict__ x,
                                              const float* __restrict__ W_rel,
                                              const float* __restrict__ W_root,
                                              const float* __restrict__ W1,
                                              const float* __restrict__ W2,
                                              int* __restrict__ part,
                                              __hip_bfloat16* __restrict__ Abuf,
                                              unsigned int* __restrict__ x8,
                                              __hip_bfloat16* __restrict__ Wc,
                                              __hip_bfloat16* __restrict__ W1b,
                                              __hip_bfloat16* __restrict__ W2b,
                                              float* __restrict__ red) {
    __shared__ int hist[NBUCK];
    int tid = threadIdx.x;
    if (blockIdx.x < NBB) {
        for (int j = tid; j < NBUCK; j += 256) hist[j] = 0;
        __syncthreads();
        int base = blockIdx.x * EPB;
        #pragma unroll
        for (int t = 0; t < EPB / 256; ++t) {
            int e = base + t * 256 + tid;
            if (e < N_EDGES) atomicAdd(&hist[clampN(dst[e]) >> 7], 1);
        }
        __syncthreads();
        for (int j = tid; j < NBUCK; j += 256)
            part[(size_t)blockIdx.x * NBUCK + j] = hist[j];
    } else {
        if (blockIdx.x == NBB) red[tid] = 0.f;
        int id = (blockIdx.x - NBB) * 256 + tid;
        if (id < CAST_X_IDS) {
            int i = id >> 5, c4 = (id & 31) * 4;
            float4 v = *(const float4*)&x[(size_t)i * 128 + c4];
            ull p = (ull)f2bfbits(v.x) | ((ull)f2bfbits(v.y) << 16)
                  | ((ull)f2bfbits(v.z) << 32) | ((ull)f2bfbits(v.w) << 48);
            *(ull*)&Abuf[(size_t)i * 256 + 128 + c4] = p;
            int t = __builtin_amdgcn_cvt_pk_fp8_f32(v.x, v.y, 0, false);
            t = __builtin_amdgcn_cvt_pk_fp8_f32(v.z, v.w, t, true);
            x8[(size_t)i * 32 + (id & 31)] = (unsigned int)t;
        } else if (id < CAST_IDS) {
            int j = id - CAST_X_IDS;
            if (j < 32768) {
                int cc = j >> 8, k = j & 255;
                float v = (k < 128) ? W_rel[cc * 128 + k] : W_root[cc * 128 + (k - 128)];
                Wc[j] = __float2bfloat16(v);
            } else if (j < 32768 + 8192) {
                W1b[j - 32768] = __float2bfloat16(W1[j - 32768]);
            } else {
                W2b[j - 32768 - 8192] = __float2bfloat16(W2[j - 32768 - 8192]);
            }
        }
    }
}

// ---------------- bucket scan: reduce partials + exclusive scan ----------------
__global__ __launch_bounds__(512) void k_bscan(const int* __restrict__ part,
                                               int* __restrict__ boff,
                                               int* __restrict__ bcur) {
    __shared__ int wsum[8];
    __shared__ int wbase[8];
    int tid = threadIdx.x;
    int lane = tid & 63, wid = tid >> 6;
    int v = 0;
    if (tid < NBUCK) {
        for (int b = 0; b < NBB; ++b) v += part[(size_t)b * NBUCK + tid];
    }
    int x = v;
    #pragma unroll
    for (int d = 1; d < 64; d <<= 1) {
        int t = __shfl_up(x, d, 64);
        if (lane >= d) x += t;
    }
    if (lane == 63) wsum[wid] = x;
    __syncthreads();
    if (tid == 0) {
        int b = 0;
        #pragma unroll
        for (int w = 0; w < 8; ++w) { wbase[w] = b; b += wsum[w]; }
    }
    __syncthreads();
    if (tid < NBUCK) {
        int e = wbase[wid] + x - v;
        boff[tid] = e;
        bcur[tid] = e;
    }
    if (tid == 0) boff[NBUCK] = N_EDGES;
}

// scatter packed (src<<7)|(dst&127) into bucket-grouped ebuf
__global__ __launch_bounds__(256) void k_bscatter(const int* __restrict__ src,
                                                  const int* __restrict__ dst,
                                                  int* __restrict__ bcur,
                                                  unsigned int* __restrict__ ebuf) {
    __shared__ int hist[NBUCK];
    __shared__ int hbase[NBUCK];
    int tid = threadIdx.x;
    for (int j = tid; j < NBUCK; j += 256) hist[j] = 0;
    __syncthreads();
    int base = blockIdx.x * EPB;
    unsigned int myP[EPB / 256]; int myB[EPB / 256], myR[EPB / 256];
    #pragma unroll
    for (int t = 0; t < EPB / 256; ++t) {
        int e = base + t * 256 + tid;
        if (e < N_EDGES) {
            int d = clampN(dst[e]);
            int s = clampN(src[e]);
            myP[t] = ((unsigned int)s << 7) | (unsigned int)(d & 127);
            myB[t] = d >> 7;
            myR[t] = atomicAdd(&hist[d >> 7], 1);
        } else myB[t] = -1;
    }
    __syncthreads();
    for (int j = tid; j < NBUCK; j += 256)
        if (hist[j]) hbase[j] = atomicAdd(&bcur[j], hist[j]);
    __syncthreads();
    #pragma unroll
    for (int t = 0; t < EPB / 256; ++t) {
        if (myB[t] >= 0) ebuf[hbase[myB[t]] + myR[t]] = myP[t];
    }
}

__global__ __launch_bounds__(256) void k_bfinal(const unsigned int* __restrict__ ebuf,
                                                const int* __restrict__ boff,
                                                int* __restrict__ offsets,
                                                int* __restrict__ csr) {
    __shared__ int cnt[128];
    __shared__ int cur[128];
    __shared__ int ws[4];
    int b = blockIdx.x;
    int tid = threadIdx.x;
    int node0 = b << 7;
    int k0 = boff[b], k1 = boff[b + 1];
    if (tid < 128) cnt[tid] = 0;
    __syncthreads();
    for (int k = k0 + tid; k < k1; k += 256)
        atomicAdd(&cnt[ebuf[k] & 127u], 1);
    __syncthreads();
    int lane = tid & 63;
    int v = (tid < 128) ? cnt[tid] : 0;
    int x = v;
    #pragma unroll
    for (int d = 1; d < 64; d <<= 1) {
        int t = __shfl_up(x, d, 64);
        if (lane >= d) x += t;
    }
    if (lane == 63) ws[tid >> 6] = x;
    __syncthreads();
    if (tid < 128) {
        int add = (tid >> 6) ? ws[0] : 0;
        int excl = k0 + add + x - v;
        cur[tid] = excl;
        int node = node0 + tid;
        if (node < N_NODES) offsets[node] = excl;
    }
    if (b == NBUCK - 1 && tid == 0) offsets[N_NODES] = N_EDGES;
    __syncthreads();
    for (int k = k0 + tid; k < k1; k += 256) {
        unsigned int e = ebuf[k];
        int r = atomicAdd(&cur[e & 127u], 1);
        csr[r] = (int)(e >> 7);
    }
}

// ---------------- GraphConv gather: fp8 x rows, 2 nodes/wave, predicated unroll 8 ----------------
__global__ __launch_bounds__(256) void k_gather(const unsigned int* __restrict__ x8,
                                                const int* __restrict__ offsets,
                                                const int* __restrict__ csr,
                                                ull* __restrict__ outNbr) {
    int i = blockIdx.x * 8 + (threadIdx.x >> 5);
    int l = threadIdx.x & 31;          // fp8 u32 word: channels 4l..4l+3
    int k0 = offsets[i], k1 = offsets[i + 1];
    float a0 = 0.f, a1 = 0.f, a2 = 0.f, a3 = 0.f;
    for (int kb = k0; kb < k1; kb += 8) {
        int s[8]; int vm[8];
        #pragma unroll
        for (int j = 0; j < 8; ++j) {
            int kk = kb + j;
            vm[j] = kk < k1;
            s[j] = csr[vm[j] ? kk : k1 - 1];
        }
        unsigned int u[8];
        #pragma unroll
        for (int j = 0; j < 8; ++j) u[j] = x8[(size_t)s[j] * 32 + l];
        #pragma unroll
        for (int j = 0; j < 8; ++j) {
            if (vm[j]) {
                f32x2 lo = __builtin_amdgcn_cvt_pk_f32_fp8(u[j], false);
                f32x2 hi = __builtin_amdgcn_cvt_pk_f32_fp8(u[j], true);
                a0 += lo.x; a1 += lo.y; a2 += hi.x; a3 += hi.y;
            }
        }
    }
    outNbr[(size_t)i * 64 + l] = (ull)pack2(a0, a1) | ((ull)pack2(a2, a3) << 32);
}

// ---------------- MFMA GEMM with LDS staging + optional fused alpha/fp8 epilogue ----------------
// EPI: 0 = plain bf16 output (ELU/BIAS apply); 1 = GAT1 alpha (8 heads) + fp8 z; 2 = GAT2 alpha (1 head) + fp8 z.
template<int K, int N, bool ELU, bool BIAS, int EPI>
__global__ __launch_bounds__(256) void k_gemm(const __hip_bfloat16* __restrict__ A,
                                              const __hip_bfloat16* __restrict__ W,
                                              const float* __restrict__ bias,
                                              __hip_bfloat16* __restrict__ Out,
                                              const float* __restrict__ a_src,
                                              const float* __restrict__ a_dst,
                                              float* __restrict__ as_o,
                                              float* __restrict__ ad_o,
                                              unsigned int* __restrict__ z8) {
    constexpr int NT = N / 16;
    __shared__ __align__(16) short smem[64 * 40 + N * 40];
    short (*sA)[40] = (short(*)[40])smem;
    short (*sW)[40] = (short(*)[40])(smem + 64 * 40);
    int tid = threadIdx.x;
    int lane = tid & 63, wave = tid >> 6;
    int quad = lane >> 4, l16 = lane & 15;
    int node0 = blockIdx.x * 64;
    int srow = tid >> 2, schk = (tid & 3) * 8;
    int ga = node0 + srow; if (ga >= N_NODES) ga = N_NODES - 1;
    const short* Ap = (const short*)A + (size_t)ga * K + schk;
    const short* Wp = (const short*)W;
    f32x4 acc[NT];
    #pragma unroll
    for (int t = 0; t < NT; ++t) acc[t] = (f32x4){0.f, 0.f, 0.f, 0.f};
    for (int k0 = 0; k0 < K; k0 += 32) {
        *(bf16x8*)&sA[srow][schk] = *(const bf16x8*)(Ap + k0);
        #pragma unroll
        for (int it = 0; it < N / 64; ++it) {
            int wrow = srow + it * 64;
            *(bf16x8*)&sW[wrow][schk] = *(const bf16x8*)(Wp + (size_t)wrow * K + k0 + schk);
        }
        __syncthreads();
        bf16x8 a = *(const bf16x8*)&sA[wave * 16 + l16][quad * 8];
        #pragma unroll
        for (int nt = 0; nt < NT; ++nt) {
            bf16x8 b = *(const bf16x8*)&sW[nt * 16 + l16][quad * 8];
            acc[nt] = __builtin_amdgcn_mfma_f32_16x16x32_bf16(a, b, acc[nt], 0, 0, 0);
        }
        __syncthreads();
    }
    if (EPI == 0) {
        int mbase = node0 + wave * 16 + quad * 4;
        #pragma unroll
        for (int nt = 0; nt < NT; ++nt) {
            int col = nt * 16 + l16;
            float bv = BIAS ? bias[col] : 0.f;
            #pragma unroll
            for (int r = 0; r < 4; ++r) {
                int m = mbase + r;
                if (m < N_NODES) {
                    float v = acc[nt][r] + bv;
                    if (ELU) v = elu_f(v);
                    Out[(size_t)m * N + col] = __float2bfloat16(v);
                }
            }
        }
    } else {
        // stage z tile to LDS (bf16, pitch 72 shorts = 16B-aligned rows), N == 64
        short* sZ = smem;
        #pragma unroll
        for (int nt = 0; nt < NT; ++nt) {
            int col = nt * 16 + l16;
            #pragma unroll
            for (int r = 0; r < 4; ++r) {
                int row = wave * 16 + quad * 4 + r;
                sZ[row * 72 + col] = (short)f2bfbits(acc[nt][r]);
            }
        }
        __syncthreads();
        int row = tid >> 2, chunk = tid & 3;       // 16 cols per thread
        int gi = node0 + row;
        float v[16];
        bf16x8 c0 = *(const bf16x8*)&sZ[row * 72 + chunk * 16];
        bf16x8 c1 = *(const bf16x8*)&sZ[row * 72 + chunk * 16 + 8];
        #pragma unroll
        for (int j = 0; j < 8; ++j) {
            v[j]     = bf2f((unsigned short)c0[j]);
            v[8 + j] = bf2f((unsigned short)c1[j]);
        }
        if (EPI == 1) {
            float ps0 = 0.f, pd0 = 0.f, ps1 = 0.f, pd1 = 0.f;
            #pragma unroll
            for (int j = 0; j < 8; ++j) {
                ps0 += v[j] * a_src[chunk * 16 + j];
                pd0 += v[j] * a_dst[chunk * 16 + j];
                ps1 += v[8 + j] * a_src[chunk * 16 + 8 + j];
                pd1 += v[8 + j] * a_dst[chunk * 16 + 8 + j];
            }
            if (gi < N_NODES) {
                as_o[(size_t)gi * 8 + 2 * chunk]     = ps0;
                as_o[(size_t)gi * 8 + 2 * chunk + 1] = ps1;
                ad_o[(size_t)gi * 8 + 2 * chunk]     = pd0;
                ad_o[(size_t)gi * 8 + 2 * chunk + 1] = pd1;
            }
        } else {
            float ps = 0.f, pd = 0.f;
            #pragma unroll
            for (int j = 0; j < 16; ++j) {
                ps += v[j] * a_src[chunk * 16 + j];
                pd += v[j] * a_dst[chunk * 16 + j];
            }
            ps += __shfl_xor(ps, 1, 64); ps += __shfl_xor(ps, 2, 64);
            pd += __shfl_xor(pd, 1, 64); pd += __shfl_xor(pd, 2, 64);
            if ((tid & 3) == 0 && gi < N_NODES) { as_o[gi] = ps; ad_o[gi] = pd; }
        }
        if (gi < N_NODES) {
            #pragma unroll
            for (int wi = 0; wi < 4; ++wi) {
                int t = __builtin_amdgcn_cvt_pk_fp8_f32(v[4 * wi], v[4 * wi + 1], 0, false);
                t = __builtin_amdgcn_cvt_pk_fp8_f32(v[4 * wi + 2], v[4 * wi + 3], t, true);
                z8[(size_t)gi * 16 + chunk * 4 + wi] = (unsigned int)t;
            }
        }
    }
}

// ---------------- GAT1 attention: fp8 z, 16 lanes/node, 8-edge batches ----------------
__global__ __launch_bounds__(256) void k_gat1attn(const unsigned int* __restrict__ z8,
                                                  const float* __restrict__ as1,
                                                  const float* __restrict__ ad1,
                                                  const float* __restrict__ b1,
                                                  const int* __restrict__ offsets,
                                                  const int* __restrict__ csr,
                                                  ull* __restrict__ h2u) {
    int i = blockIdx.x * 16 + (threadIdx.x >> 4);
    int l = threadIdx.x & 15;      // channels 4l..4l+3 ; head hd = l>>1
    int hd = l >> 1;
    int wh = l & 7, slot = l >> 3; // weight phase: 2 slots x 8 heads
    int k0 = offsets[i], k1 = offsets[i + 1];
    float ad_h = ad1[(size_t)i * 8 + hd];
    float adw  = ad1[(size_t)i * 8 + wh];
    float e_self = __expf(lrelu_f(as1[(size_t)i * 8 + hd] + ad_h));
    unsigned int uz = z8[(size_t)i * 16 + l];
    f32x2 zlo = __builtin_amdgcn_cvt_pk_f32_fp8(uz, false);
    f32x2 zhi = __builtin_amdgcn_cvt_pk_f32_fp8(uz, true);
    float acc0 = e_self * zlo.x, acc1 = e_self * zlo.y;
    float acc2 = e_self * zhi.x, acc3 = e_self * zhi.y;
    float denp = 0.f;
    for (int kb = k0; kb < k1; kb += 8) {
        int sr[4]; float er[4];
        #pragma unroll
        for (int m = 0; m < 4; ++m) {
            int kk = kb + 2 * m + slot;
            bool v = kk < k1;
            int s = csr[v ? kk : k1 - 1];
            sr[m] = s;
            er[m] = v ? __expf(lrelu_f(as1[(size_t)s * 8 + wh] + adw)) : 0.f;
            denp += er[m];
        }
        int sj[8]; float ej[8]; unsigned int u[8];
        #pragma unroll
        for (int m = 0; m < 4; ++m) {
            #pragma unroll
            for (int sb = 0; sb < 2; ++sb) {
                sj[2 * m + sb] = __shfl(sr[m], sb * 8 + hd, 16);
                ej[2 * m + sb] = __shfl(er[m], sb * 8 + hd, 16);
            }
        }
        #pragma unroll
        for (int j = 0; j < 8; ++j) u[j] = z8[(size_t)sj[j] * 16 + l];
        #pragma unroll
        for (int j = 0; j < 8; ++j) {
            f32x2 alo = __builtin_amdgcn_cvt_pk_f32_fp8(u[j], false);
            f32x2 ahi = __builtin_amdgcn_cvt_pk_f32_fp8(u[j], true);
            acc0 += ej[j] * alo.x; acc1 += ej[j] * alo.y;
            acc2 += ej[j] * ahi.x; acc3 += ej[j] * ahi.y;
        }
    }
    denp += __shfl_xor(denp, 8, 16);
    float den = __shfl(denp, hd, 16) + e_self;
    float inv = 1.f / den;
    float r0 = elu_f(acc0 * inv + b1[4 * l + 0]);
    float r1 = elu_f(acc1 * inv + b1[4 * l + 1]);
    float r2 = elu_f(acc2 * inv + b1[4 * l + 2]);
    float r3 = elu_f(acc3 * inv + b1[4 * l + 3]);
    h2u[(size_t)i * 16 + l] = (ull)pack2(r0, r1) | ((ull)pack2(r2, r3) << 32);
}

// ---------------- GAT2 attention: fp8 z, 16 lanes/node, 8-row inner batches, fused dot ----------------
__global__ __launch_bounds__(256) void k_gat2attn(const unsigned int* __restrict__ z8,
                                                  const float* __restrict__ as2,
                                                  const float* __restrict__ ad2,
                                                  const float* __restrict__ b2,
                                                  const int* __restrict__ offsets,
                                                  const int* __restrict__ csr,
                                                  const float* __restrict__ Wr,
                                                  float* __restrict__ red) {
    int i = blockIdx.x * 16 + (threadIdx.x >> 4);
    int l = threadIdx.x & 15;
    int k0 = offsets[i], k1 = offsets[i + 1];
    float ad = ad2[i];
    float e_self = __expf(lrelu_f(as2[i] + ad));
    unsigned int uz = z8[(size_t)i * 16 + l];
    f32x2 zlo = __builtin_amdgcn_cvt_pk_f32_fp8(uz, false);
    f32x2 zhi = __builtin_amdgcn_cvt_pk_f32_fp8(uz, true);
    float acc0 = e_self * zlo.x, acc1 = e_self * zlo.y;
    float acc2 = e_self * zhi.x, acc3 = e_self * zhi.y;
    float denp = (l == 0) ? e_self : 0.f;
    for (int kb = k0; kb < k1; kb += 16) {
        int kk = kb + l;
        bool v = kk < k1;
        int s = csr[v ? kk : k1 - 1];
        float e = v ? __expf(lrelu_f(as2[s] + ad)) : 0.f;
        denp += e;
        int nv = k1 - kb; if (nv > 16) nv = 16;
        for (int j0 = 0; j0 < nv; j0 += 8) {
            int sj[8]; float ej[8]; unsigned int u[8];
            #pragma unroll
            for (int j = 0; j < 8; ++j) {
                int idx = (j0 + j) & 15;
                sj[j] = __shfl(s, idx, 16);
                ej[j] = __shfl(e, idx, 16);
            }
            #pragma unroll
            for (int j = 0; j < 8; ++j) u[j] = z8[(size_t)sj[j] * 16 + l];
            #pragma unroll
            for (int j = 0; j < 8; ++j) {
                f32x2 alo = __builtin_amdgcn_cvt_pk_f32_fp8(u[j], false);
                f32x2 ahi = __builtin_amdgcn_cvt_pk_f32_fp8(u[j], true);
                acc0 += ej[j] * alo.x; acc1 += ej[j] * alo.y;
                acc2 += ej[j] * ahi.x; acc3 += ej[j] * ahi.y;
            }
        }
    }
    #pragma unroll
    for (int d = 8; d >= 1; d >>= 1) denp += __shfl_xor(denp, d, 16);
    float inv = 1.f / denp;
    float c = (acc0 * inv + b2[4 * l + 0]) * Wr[4 * l + 0]
            + (acc1 * inv + b2[4 * l + 1]) * Wr[4 * l + 1]
            + (acc2 * inv + b2[4 * l + 2]) * Wr[4 * l + 2]
            + (acc3 * inv + b2[4 * l + 3]) * Wr[4 * l + 3];
    #pragma unroll
    for (int d = 8; d >= 1; d >>= 1) c += __shfl_xor(c, d, 16);
    if (l == 0) atomicAdd(&red[blockIdx.x & 255], c);
}

// ---------------- finalize ----------------
__global__ void k_finalize(const float* __restrict__ red, const float* __restrict__ br,
                           float* __restrict__ out) {
    int t = threadIdx.x;    // 64 threads
    float s = red[t] + red[t + 64] + red[t + 128] + red[t + 192];
    #pragma unroll
    for (int d = 32; d >= 1; d >>= 1) s += __shfl_xor(s, d, 64);
    if (t == 0) out[0] = s * (1.0f / N_NODES) + br[0];
}

extern "C" void kernel_launch(void* const* d_in, const int* in_sizes, int n_in,
                              void* d_out, int out_size, void* d_ws, size_t ws_size,
                              hipStream_t stream) {
    const float* x      = (const float*)d_in[0];
    const int*   edges  = (const int*)d_in[1];
    const float* W_rel  = (const float*)d_in[2];
    const float* b_rel  = (const float*)d_in[3];
    const float* W_root = (const float*)d_in[4];
    const float* W1     = (const float*)d_in[5];
    const float* a1s    = (const float*)d_in[6];
    const float* a1d    = (const float*)d_in[7];
    const float* b1     = (const float*)d_in[8];
    const float* W2     = (const float*)d_in[9];
    const float* a2s    = (const float*)d_in[10];
    const float* a2d    = (const float*)d_in[11];
    const float* b2     = (const float*)d_in[12];
    const float* Wr     = (const float*)d_in[13];
    const float* br     = (const float*)d_in[14];
    float* out = (float*)d_out;

    const int* src = edges;
    const int* dst = edges + N_EDGES;

    char* ws = (char*)d_ws;
    size_t p = 0;
    auto alloc = [&](size_t bytes) -> void* {
        void* r = ws + p;
        p = (p + bytes + 255) & ~(size_t)255;
        return r;
    };
    int*   part    = (int*)alloc((size_t)NBB * NBUCK * 4);          // hist partials
    int*   boff    = (int*)alloc((size_t)(NBUCK + 1) * 4);
    int*   bcur    = (int*)alloc((size_t)NBUCK * 4);
    unsigned int* ebuf = (unsigned int*)alloc((size_t)N_EDGES * 4); // packed (src<<7)|dstlocal
    int*   offsets = (int*)alloc((size_t)(N_NODES + 1) * 4);
    int*   csr     = (int*)alloc((size_t)N_EDGES * 4);
    __hip_bfloat16* Abuf = (__hip_bfloat16*)alloc((size_t)N_NODES * 256 * 2);  // [nbr | x]
    unsigned int* x8 = (unsigned int*)alloc((size_t)N_NODES * 32 * 4);         // fp8 x
    __hip_bfloat16* Wc   = (__hip_bfloat16*)alloc((size_t)128 * 256 * 2);
    __hip_bfloat16* W1b  = (__hip_bfloat16*)alloc((size_t)64 * 128 * 2);
    __hip_bfloat16* W2b  = (__hip_bfloat16*)alloc((size_t)64 * 64 * 2);
    __hip_bfloat16* h    = (__hip_bfloat16*)alloc((size_t)N_NODES * 128 * 2);
    float* as1 = (float*)alloc((size_t)N_NODES * 8 * 4);
    float* ad1 = (float*)alloc((size_t)N_NODES * 8 * 4);
    __hip_bfloat16* h2b  = (__hip_bfloat16*)alloc((size_t)N_NODES * 64 * 2);
    float* as2 = (float*)alloc((size_t)N_NODES * 4);
    float* ad2 = (float*)alloc((size_t)N_NODES * 4);
    unsigned int* z1e8 = (unsigned int*)alloc((size_t)N_NODES * 16 * 4);  // fp8 z1
    unsigned int* z2e8 = (unsigned int*)alloc((size_t)N_NODES * 16 * 4);  // fp8 z2
    float* red = (float*)alloc(256 * 4);

    const int MB   = (N_NODES + 63) / 64;   // 782
    const int NB8  = N_NODES / 8;           // 6250
    const int NB16 = N_NODES / 16;          // 3125

    k_prep    <<<NBB + CASTB, 256, 0, stream>>>(dst, x, W_rel, W_root, W1, W2,
                                                part, Abuf, x8, Wc, W1b, W2b, red);
    k_bscan   <<<1, 512, 0, stream>>>(part, boff, bcur);
    k_bscatter<<<NBB, 256, 0, stream>>>(src, dst, bcur, ebuf);
    k_bfinal  <<<NBUCK, 256, 0, stream>>>(ebuf, boff, offsets, csr);
    k_gather  <<<NB8, 256, 0, stream>>>(x8, offsets, csr, (ull*)Abuf);
    k_gemm<256, 128, true,  true,  0><<<MB, 256, 0, stream>>>(Abuf, Wc, b_rel, h,
                                                              nullptr, nullptr, nullptr, nullptr, nullptr);
    k_gemm<128, 64,  false, false, 1><<<MB, 256, 0, stream>>>(h, W1b, nullptr, nullptr,
                                                              a1s, a1d, as1, ad1, z1e8);
    k_gat1attn<<<NB16, 256, 0, stream>>>(z1e8, as1, ad1, b1, offsets, csr, (ull*)h2b);
    k_gemm<64, 64, false, false, 2><<<MB, 256, 0, stream>>>(h2b, W2b, nullptr, nullptr,
                                                            a2s, a2d, as2, ad2, z2e8);
    k_gat2attn<<<NB16, 256, 0, stream>>>(z2e8, as2, ad2, b2, offsets, csr, Wr, red);
    k_finalize<<<1, 64, 0, stream>>>(red, br, out);
}